// Round 1
// baseline (20672.235 us; speedup 1.0000x reference)
//
#include <hip/hip_runtime.h>

typedef unsigned short u16;

// ---------- bf16 helpers (manual, to avoid __hip_bfloat16 ABI differences) ----------
static __device__ __forceinline__ float bf2f(u16 u) {
  return __uint_as_float(((unsigned)u) << 16);
}
static __device__ __forceinline__ u16 f2bf(float f) {
  unsigned u = __float_as_uint(f);
  u += 0x7fffu + ((u >> 16) & 1u);  // round-to-nearest-even
  return (u16)(u >> 16);
}
static __device__ __forceinline__ float sigmoidf_(float x) {
  return 1.f / (1.f + __expf(-x));
}

// Sizes
#define VOCAB 32000
#define EMBED 512
#define HIDDEN 1024
#define BATCH 64
#define SEQ 512
#define G4H 4096  // 4*HIDDEN

// =====================================================================
// Phase A: xp[m][g] = emb_table[x[m]] . W_ih[g] + b_ih[g] + b_hh[g]
// m = b*SEQ + t in [0, 32768), g in [0, 4096). Output bf16.
// Tiled f32 GEMM: 64x64 tile, BK=32, 256 threads, 4x4 per thread.
// =====================================================================
__global__ __launch_bounds__(256) void phaseA(
    const int* __restrict__ x, const float* __restrict__ emb,
    const float* __restrict__ Wih, const float* __restrict__ bih,
    const float* __restrict__ bhh, u16* __restrict__ xp) {
  __shared__ float As[32][65];
  __shared__ float Bs[32][65];
  __shared__ int rows[64];
  const int t = threadIdx.x;
  const int bx = blockIdx.x, by = blockIdx.y;
  if (t < 64) rows[t] = x[by * 64 + t];
  __syncthreads();
  const int tx = t & 15, ty = t >> 4;
  float acc[4][4];
#pragma unroll
  for (int i = 0; i < 4; ++i)
#pragma unroll
    for (int j = 0; j < 4; ++j) acc[i][j] = 0.f;

  for (int k0 = 0; k0 < EMBED; k0 += 32) {
#pragma unroll
    for (int i = 0; i < 8; ++i) {
      int e = t + i * 256;
      int m = e >> 5, k = e & 31;
      As[k][m] = emb[(size_t)rows[m] * EMBED + k0 + k];
      Bs[k][m] = Wih[((size_t)bx * 64 + m) * EMBED + k0 + k];
    }
    __syncthreads();
#pragma unroll
    for (int kk = 0; kk < 32; ++kk) {
      float a[4], b[4];
#pragma unroll
      for (int i = 0; i < 4; ++i) a[i] = As[kk][ty * 4 + i];
#pragma unroll
      for (int j = 0; j < 4; ++j) b[j] = Bs[kk][tx * 4 + j];
#pragma unroll
      for (int i = 0; i < 4; ++i)
#pragma unroll
        for (int j = 0; j < 4; ++j) acc[i][j] = fmaf(a[i], b[j], acc[i][j]);
    }
    __syncthreads();
  }
#pragma unroll
  for (int i = 0; i < 4; ++i) {
    const int gm = by * 64 + ty * 4 + i;
#pragma unroll
    for (int j = 0; j < 4; ++j) {
      const int gn = bx * 64 + tx * 4 + j;
      float v = acc[i][j] + bih[gn] + bhh[gn];
      xp[(size_t)gm * G4H + gn] = f2bf(v);
    }
  }
}

// =====================================================================
// Phase B: one timestep. grid=256 blocks (4 hidden units each), 512 thr.
// Wave w handles K-slice [w*128, w*128+128). Lanes = batch (64).
// h stored TRANSPOSED in global: hT[k][b], bf16 -> coalesced 128B reads.
// W_hh addresses are wave-uniform (blockIdx + unrolled loop constants).
// Partials reduced across the 8 waves via LDS, then gate math.
// =====================================================================
__global__ __launch_bounds__(512) void phaseB(
    const u16* __restrict__ xp, const float* __restrict__ Whh,
    const u16* __restrict__ hT, u16* __restrict__ hTn, float* __restrict__ c,
    int tstep) {
  __shared__ float ps[8][16][64];
  const int t = threadIdx.x;
  const int wave = t >> 6;
  const int b = t & 63;
  const int u0 = blockIdx.x * 4;
  const int k0 = wave * 128;
  float acc[16];
#pragma unroll
  for (int r = 0; r < 16; ++r) acc[r] = 0.f;

  for (int kc = 0; kc < 128; kc += 4) {
    float hv[4];
#pragma unroll
    for (int j = 0; j < 4; ++j) hv[j] = bf2f(hT[(k0 + kc + j) * 64 + b]);
#pragma unroll
    for (int r = 0; r < 16; ++r) {
      const int row = (r >> 2) * HIDDEN + u0 + (r & 3);  // r = gate*4 + u
      const float4 w = *(const float4*)(Whh + (size_t)row * HIDDEN + k0 + kc);
      acc[r] = fmaf(hv[0], w.x, acc[r]);
      acc[r] = fmaf(hv[1], w.y, acc[r]);
      acc[r] = fmaf(hv[2], w.z, acc[r]);
      acc[r] = fmaf(hv[3], w.w, acc[r]);
    }
  }
#pragma unroll
  for (int r = 0; r < 16; ++r) ps[wave][r][b] = acc[r];
  __syncthreads();
  if (t < 256) {
    const int bb = t & 63, u = t >> 6;
    float g4[4];
#pragma unroll
    for (int g = 0; g < 4; ++g) {
      float s = bf2f(xp[((size_t)bb * SEQ + tstep) * G4H + g * HIDDEN + u0 + u]);
#pragma unroll
      for (int w = 0; w < 8; ++w) s += ps[w][g * 4 + u][bb];
      g4[g] = s;
    }
    const float ig = sigmoidf_(g4[0]);
    const float fg = sigmoidf_(g4[1]);
    const float gg = tanhf(g4[2]);
    const float og = sigmoidf_(g4[3]);
    const size_t ci = (size_t)bb * HIDDEN + u0 + u;
    const float cn = fg * c[ci] + ig * gg;
    c[ci] = cn;
    hTn[(u0 + u) * 64 + bb] = f2bf(og * tanhf(cn));
  }
}

// =====================================================================
// Phase C: out[b][v] = sum_k hT[k][b] * W_fc[v][k] + b_fc[v]
// grid = 1000 blocks (32 vocab rows each), 256 threads.
// K chunked by 256; W chunk + h chunk staged in LDS.
// =====================================================================
__global__ __launch_bounds__(256) void phaseC(
    const u16* __restrict__ hT, const float* __restrict__ Wfc,
    const float* __restrict__ bfc, float* __restrict__ out) {
  __shared__ float Ws[32][257];
  __shared__ __align__(16) u16 hs[256][64];
  const int t = threadIdx.x;
  const int v0 = blockIdx.x * 32;
  const int lane = t & 63;
  const int w = t >> 6;
  const int v = lane & 31;
  const int bbase = ((w << 1) | (lane >> 5)) << 3;  // (w*2 + bh)*8
  float acc[8];
#pragma unroll
  for (int i = 0; i < 8; ++i) acc[i] = 0.f;

  for (int kc = 0; kc < HIDDEN; kc += 256) {
#pragma unroll
    for (int i = 0; i < 32; ++i) {
      int e = t + i * 256;
      int vv = e >> 8, k = e & 255;
      Ws[vv][k] = Wfc[((size_t)(v0 + vv)) * HIDDEN + kc + k];
    }
#pragma unroll
    for (int i = 0; i < 16; ++i) {
      int e = t + i * 256;
      int k = e >> 4, b4 = e & 15;
      *(ushort4*)&hs[k][b4 * 4] =
          *(const ushort4*)&hT[(size_t)(kc + k) * 64 + b4 * 4];
    }
    __syncthreads();
    for (int k = 0; k < 256; ++k) {
      const float wv = Ws[v][k];
      const uint4 h4 = *(const uint4*)&hs[k][bbase];
      acc[0] = fmaf(wv, __uint_as_float(h4.x << 16), acc[0]);
      acc[1] = fmaf(wv, __uint_as_float(h4.x & 0xffff0000u), acc[1]);
      acc[2] = fmaf(wv, __uint_as_float(h4.y << 16), acc[2]);
      acc[3] = fmaf(wv, __uint_as_float(h4.y & 0xffff0000u), acc[3]);
      acc[4] = fmaf(wv, __uint_as_float(h4.z << 16), acc[4]);
      acc[5] = fmaf(wv, __uint_as_float(h4.z & 0xffff0000u), acc[5]);
      acc[6] = fmaf(wv, __uint_as_float(h4.w << 16), acc[6]);
      acc[7] = fmaf(wv, __uint_as_float(h4.w & 0xffff0000u), acc[7]);
    }
    __syncthreads();
  }
  const float bias = bfc[v0 + v];
#pragma unroll
  for (int i = 0; i < 8; ++i) {
    out[(size_t)(bbase + i) * VOCAB + v0 + v] = acc[i] + bias;
  }
}

// =====================================================================
extern "C" void kernel_launch(void* const* d_in, const int* in_sizes, int n_in,
                              void* d_out, int out_size, void* d_ws,
                              size_t ws_size, hipStream_t stream) {
  const int* x = (const int*)d_in[0];
  const float* emb = (const float*)d_in[1];
  const float* Wih = (const float*)d_in[2];
  const float* Whh = (const float*)d_in[3];
  const float* bih = (const float*)d_in[4];
  const float* bhh = (const float*)d_in[5];
  const float* Wfc = (const float*)d_in[6];
  const float* bfc = (const float*)d_in[7];
  float* out = (float*)d_out;

  char* ws = (char*)d_ws;
  const size_t XP_BYTES = (size_t)BATCH * SEQ * G4H * sizeof(u16);  // 256 MB
  u16* xp = (u16*)ws;
  u16* h0 = (u16*)(ws + XP_BYTES);
  u16* h1 = (u16*)(ws + XP_BYTES + 131072);
  float* c = (float*)(ws + XP_BYTES + 262144);

  // zero h0, h1, c (contiguous 512 KB)
  hipMemsetAsync(h0, 0, 131072 + 131072 + 262144, stream);

  phaseA<<<dim3(64, 512), 256, 0, stream>>>(x, emb, Wih, bih, bhh, xp);

  for (int ts = 0; ts < SEQ; ++ts) {
    const u16* hp = (ts & 1) ? h1 : h0;
    u16* hn = (ts & 1) ? h0 : h1;
    phaseB<<<256, 512, 0, stream>>>(xp, Whh, hp, hn, c, ts);
  }

  // SEQ is even -> final h lives in h0
  phaseC<<<1000, 256, 0, stream>>>(h0, Wfc, bfc, out);
}